// Round 10
// baseline (262.299 us; speedup 1.0000x reference)
//
#include <hip/hip_runtime.h>
#include <cstddef>

#define A_ATOMS 96
#define BATCH   128
#define NNODES  12288   // B*A
#define NB      8       // nodes per block (node_k)
#define AS      132     // AsL / workS stride (132%32=4)
#define XS      196     // xinS stride (196%32=4)
#define PSTR    240     // P row stride per node: 30 h * 8 floats

typedef float v2f __attribute__((ext_vector_type(2)));
typedef unsigned long long u64;

__device__ __forceinline__ float silu_f(float x) {
    float e = __expf(-x);
    return x * __builtin_amdgcn_rcpf(1.0f + e);
}

// ---- packed f32 FMA (CDNA VOP3P, full-rate 2xFMA): acc = a*w + acc ---------
// w is a wave-uniform 64-bit weight pair -> SGPR operand (1 const-bus slot).
// _lo/_hi broadcast the low/high half of `a` to both lanes via op_sel.
__device__ __forceinline__ void pkfma(v2f& acc, v2f a, u64 w) {
    asm("v_pk_fma_f32 %0, %1, %2, %0" : "+v"(acc) : "v"(a), "s"(w));
}
__device__ __forceinline__ void pkfma_lo(v2f& acc, v2f a, u64 w) {
    asm("v_pk_fma_f32 %0, %1, %2, %0 op_sel:[0,0,0] op_sel_hi:[0,1,1]"
        : "+v"(acc) : "v"(a), "s"(w));
}
__device__ __forceinline__ void pkfma_hi(v2f& acc, v2f a, u64 w) {
    asm("v_pk_fma_f32 %0, %1, %2, %0 op_sel:[1,0,0] op_sel_hi:[1,1,1]"
        : "+v"(acc) : "v"(a), "s"(w));
}
__device__ __forceinline__ u64 ldw2(const float* p) {
    u64 w; __builtin_memcpy(&w, p, 8); return w;   // 4B-aligned-safe pair load
}

#define RED64(v) { v += __shfl_xor(v, 1); v += __shfl_xor(v, 2); v += __shfl_xor(v, 4); \
                   v += __shfl_xor(v, 8); v += __shfl_xor(v, 16); v += __shfl_xor(v, 32); }
#define RED16(v) { v += __shfl_xor(v, 1); v += __shfl_xor(v, 2); v += __shfl_xor(v, 4); \
                   v += __shfl_xor(v, 8); }

// ===== fused node kernel: R7 version unchanged (R2 body + P-emit tail) ======
__global__ __launch_bounds__(128, 3)
void node_k(const float* __restrict__ vrep, const float* __restrict__ mixW1,
            const float* __restrict__ srep,
            const float* __restrict__ sc1W1, const float* __restrict__ sc1b1,
            const float* __restrict__ sc1W2, const float* __restrict__ sc1b2,
            const float* __restrict__ mixW2,
            const float* __restrict__ sc2W1, const float* __restrict__ sc2b1,
            const float* __restrict__ sc2W2, const float* __restrict__ sc2b2,
            const float* __restrict__ pos,
            const float* __restrict__ vvW1, const float* __restrict__ vrW1,
            const float* __restrict__ sW1,  const float* __restrict__ sb1,
            float* __restrict__ l0v, float* __restrict__ l1v,
            float* __restrict__ P) {
    __shared__ float AsL[24 * AS];
    __shared__ float xinS[NB * XS];
    __shared__ float s1s[2][4][64];
    __shared__ float pwp[NB][6];
    __shared__ float gateS[NB], l0S[NB];

    const int t  = threadIdx.x;
    const int w  = t >> 6;
    const int ln = t & 63;
    const int cx = ln & 15;
    const int ry = ln >> 4;
    const int cb = w * 64 + cx * 4;
    const int row0  = blockIdx.x * 24;
    const int node0 = blockIdx.x * NB;

#pragma unroll
    for (int it = 0; it < 6; it++) {
        const int idx = it * 128 + t;
        const int r   = idx >> 5;
        const int c4  = (idx & 31) * 4;
        *(float4*)&AsL[r * AS + c4] = *(const float4*)(vrep + (size_t)(row0 + r) * 128 + c4);
    }
#pragma unroll
    for (int it = 0; it < 2; it++) {
        const int idx = it * 128 + t;
        const int a   = idx >> 5;
        const int c4  = (idx & 31) * 4;
        *(float4*)&xinS[a * XS + c4] = *(const float4*)(srep + (size_t)(node0 + a) * 128 + c4);
    }
    __syncthreads();

    float acc[2][3][4];
#pragma unroll
    for (int p = 0; p < 2; p++)
#pragma unroll
        for (int d = 0; d < 3; d++)
#pragma unroll
            for (int j = 0; j < 4; j++) acc[p][d][j] = 0.0f;

    for (int kc = 0; kc < 128; kc += 8) {
        float a[2][3][8];
#pragma unroll
        for (int p = 0; p < 2; p++)
#pragma unroll
            for (int d = 0; d < 3; d++) {
                const int row = (3 * (ry + 4 * p) + d) * AS + kc;
                *(float4*)&a[p][d][0] = *(const float4*)&AsL[row];
                *(float4*)&a[p][d][4] = *(const float4*)&AsL[row + 4];
            }
#pragma unroll
        for (int kk = 0; kk < 8; kk++) {
            float b[4];
            *(float4*)b = *(const float4*)(mixW1 + (size_t)(kc + kk) * 128 + cb);
#pragma unroll
            for (int p = 0; p < 2; p++)
#pragma unroll
                for (int d = 0; d < 3; d++)
#pragma unroll
                    for (int j = 0; j < 4; j++)
                        acc[p][d][j] += a[p][d][kk] * b[j];
        }
    }
    if (w == 0) {
#pragma unroll
        for (int p = 0; p < 2; p++) {
            float nrm[4];
#pragma unroll
            for (int c = 0; c < 4; c++)
                nrm[c] = sqrtf(acc[p][0][c] * acc[p][0][c] + acc[p][1][c] * acc[p][1][c]
                             + acc[p][2][c] * acc[p][2][c]);
            *(float4*)&xinS[(ry + 4 * p) * XS + 128 + cb] = *(float4*)nrm;
        }
    }
    __syncthreads();

    float* workS = AsL;
    {
        float acc3[2][4];
#pragma unroll
        for (int p = 0; p < 2; p++)
#pragma unroll
            for (int j = 0; j < 4; j++) acc3[p][j] = 0.0f;
        for (int kc = 0; kc < 192; kc += 8) {
            float af[2][8];
#pragma unroll
            for (int p = 0; p < 2; p++) {
                const int row = (ry + 4 * p) * XS + kc;
                *(float4*)&af[p][0] = *(const float4*)&xinS[row];
                *(float4*)&af[p][4] = *(const float4*)&xinS[row + 4];
            }
#pragma unroll
            for (int kk = 0; kk < 8; kk++) {
                float b[4];
                *(float4*)b = *(const float4*)(sc1W1 + (size_t)(kc + kk) * 128 + cb);
#pragma unroll
                for (int p = 0; p < 2; p++)
#pragma unroll
                    for (int j = 0; j < 4; j++) acc3[p][j] += af[p][kk] * b[j];
            }
        }
#pragma unroll
        for (int p = 0; p < 2; p++) {
            float h[4];
#pragma unroll
            for (int j = 0; j < 4; j++) h[j] = silu_f(acc3[p][j] + sc1b1[cb + j]);
            *(float4*)&workS[(ry + 4 * p) * AS + cb] = *(float4*)h;
        }
    }
    __syncthreads();

    float xg[2][4];
    {
        float acc4[2][4];
#pragma unroll
        for (int p = 0; p < 2; p++)
#pragma unroll
            for (int j = 0; j < 4; j++) acc4[p][j] = 0.0f;
        for (int kc = 0; kc < 128; kc += 8) {
            float af[2][8];
#pragma unroll
            for (int p = 0; p < 2; p++) {
                const int row = (ry + 4 * p) * AS + kc;
                *(float4*)&af[p][0] = *(const float4*)&workS[row];
                *(float4*)&af[p][4] = *(const float4*)&workS[row + 4];
            }
#pragma unroll
            for (int kk = 0; kk < 8; kk++) {
                float b[4];
                *(float4*)b = *(const float4*)(sc1W2 + (size_t)(kc + kk) * 128 + cb);
#pragma unroll
                for (int p = 0; p < 2; p++)
#pragma unroll
                    for (int j = 0; j < 4; j++) acc4[p][j] += af[p][kk] * b[j];
            }
        }
        if (w == 0) {
#pragma unroll
            for (int p = 0; p < 2; p++) {
                float xs[4];
#pragma unroll
                for (int j = 0; j < 4; j++) xs[j] = acc4[p][j] + sc1b2[cb + j];
                *(float4*)&xinS[(ry + 4 * p) * XS + cb] = *(float4*)xs;
            }
        } else {
#pragma unroll
            for (int p = 0; p < 2; p++)
#pragma unroll
                for (int j = 0; j < 4; j++) xg[p][j] = acc4[p][j] + sc1b2[cb + j];
        }
    }

    if (w == 1) {
#pragma unroll
        for (int p = 0; p < 2; p++) {
            float p0 = 0, p1 = 0, p2 = 0, p3 = 0, p4 = 0, p5 = 0;
#pragma unroll
            for (int c = 0; c < 4; c++) {
                float2 m = *(const float2*)(mixW2 + (size_t)(cb - 64 + c) * 2);
                const float v0 = xg[p][c] * acc[p][0][c];
                const float v1 = xg[p][c] * acc[p][1][c];
                const float v2 = xg[p][c] * acc[p][2][c];
                p0 += v0 * m.x; p1 += v0 * m.y;
                p2 += v1 * m.x; p3 += v1 * m.y;
                p4 += v2 * m.x; p5 += v2 * m.y;
            }
            RED16(p0); RED16(p1); RED16(p2); RED16(p3); RED16(p4); RED16(p5);
            if (cx == 0) {
                const int nl = ry + 4 * p;
                pwp[nl][0] = p0; pwp[nl][1] = p1;
                pwp[nl][2] = p2; pwp[nl][3] = p3;
                pwp[nl][4] = p4; pwp[nl][5] = p5;
            }
        }
    }
    __syncthreads();

    {
        const float bb1 = sc2b1[ln];
        const float wn  = sc2W1[64 * 64 + ln];
        const float wq0 = sc2W2[ln * 2 + 0], wq1 = sc2W2[ln * 2 + 1];
        float vn2[4], g0[4], g1[4], g2[4];
#pragma unroll
        for (int r = 0; r < 4; r++) {
            const int nl = r * 2 + w;
            const float q00 = pwp[nl][0], q10 = pwp[nl][2], q20 = pwp[nl][4];
            vn2[r] = sqrtf(q00 * q00 + q10 * q10 + q20 * q20);
            g0[r] = pwp[nl][1]; g1[r] = pwp[nl][3]; g2[r] = pwp[nl][5];
            s1s[w][r][ln] = silu_f(xinS[nl * XS + ln]);
        }
        __builtin_amdgcn_s_waitcnt(0);
        float acc5[4];
#pragma unroll
        for (int r = 0; r < 4; r++) acc5[r] = bb1 + vn2[r] * wn;
#pragma unroll 8
        for (int i2 = 0; i2 < 64; i2++) {
            const float wv = sc2W1[i2 * 64 + ln];
#pragma unroll
            for (int r = 0; r < 4; r++) acc5[r] += s1s[w][r][i2] * wv;
        }
#pragma unroll
        for (int r = 0; r < 4; r++) {
            const float h2 = silu_f(acc5[r]);
            float q0 = h2 * wq0, q1 = h2 * wq1;
            RED64(q0); RED64(q1);
            if (ln == 0) {
                const int nl = r * 2 + w;
                const int n = node0 + nl;
                const float gate = q1 + sc2b2[1];
                const float l0o  = q0 + sc2b2[0];
                l0v[n] = l0o;
                l1v[(size_t)n * 3 + 0] = gate * g0[r];
                l1v[(size_t)n * 3 + 1] = gate * g1[r];
                l1v[(size_t)n * 3 + 2] = gate * g2[r];
                gateS[nl] = gate;
                l0S[nl]   = l0o;
            }
        }
    }
    __syncthreads();

    // P-emit tail: layout [node][h<30][8] = {pv0,pv1,pv2,pr0,pr1,pr2,ps,0}
    {
        const int nl = t >> 4;          // 0..7
        const int q  = t & 15;          // 0..15
        const int n  = node0 + nl;
        const float lj0 = gateS[nl] * pwp[nl][1];
        const float lj1 = gateS[nl] * pwp[nl][3];
        const float lj2 = gateS[nl] * pwp[nl][5];
        const float l0j = l0S[nl];
        const float pj0 = pos[n * 3 + 0], pj1 = pos[n * 3 + 1], pj2 = pos[n * 3 + 2];
        float* Pj = P + (size_t)n * PSTR;
        for (int h = q; h < 30; h += 16) {
            float o[8];
#pragma unroll
            for (int a = 0; a < 3; a++) {
                o[a]     = lj0 * vvW1[(3 * a + 0) * 30 + h]
                         + lj1 * vvW1[(3 * a + 1) * 30 + h]
                         + lj2 * vvW1[(3 * a + 2) * 30 + h];
                o[3 + a] = pj0 * vrW1[(3 * a + 0) * 30 + h]
                         + pj1 * vrW1[(3 * a + 1) * 30 + h]
                         + pj2 * vrW1[(3 * a + 2) * 30 + h];
            }
            o[6] = sb1[h] + l0j * sW1[30 + h];
            o[7] = 0.0f;
            *(float4*)&Pj[h * 8 + 0] = *(float4*)&o[0];
            *(float4*)&Pj[h * 8 + 4] = *(float4*)&o[4];
        }
    }
}

// ---------- pair kernel v8: pk_fma + FULL h-loop unroll ---------------------
// Grid (A/4, B), 192 threads. All Pj float4 offsets (h*32B) and weight-pair
// offsets become compile-time immediates -> scheduler free to hoist VMEM/SMEM
// loads many iterations ahead (VGPR 32 -> ample headroom). Tests hypothesis:
// R9's 27us stall = per-iteration load latency exposure.
__global__ __launch_bounds__(192)
void pair_k(const float* __restrict__ l0v, const float* __restrict__ l1v,
            const float* __restrict__ P,
            const float* __restrict__ vvb1, const float* __restrict__ vrb1,
            const float* __restrict__ sW1,
            const float* __restrict__ vvW2, const float* __restrict__ vrW2,
            const float* __restrict__ sW2,
            const float* __restrict__ vvb2, const float* __restrict__ vrb2,
            const float* __restrict__ sb2,
            const float* __restrict__ hW1,  const float* __restrict__ hb1,
            const float* __restrict__ hW2,  const float* __restrict__ hb2,
            float* __restrict__ out) {
    const int t = threadIdx.x;
    const int b = blockIdx.y;
    const int g = (t >= 96) ? 1 : 0;
    const int j = t - g * 96;
    const int i0 = blockIdx.x * 4 + g * 2;
    const int ni0 = b * A_ATOMS + i0;       // thread: i = ni0, ni0+1
    const int nj  = b * A_ATOMS + j;
    const float* Pj = P + (size_t)nj * PSTR;

    const float li0x = l1v[ni0 * 3 + 0], li0y = l1v[ni0 * 3 + 1], li0z = l1v[ni0 * 3 + 2];
    const float li1x = l1v[(ni0 + 1) * 3 + 0], li1y = l1v[(ni0 + 1) * 3 + 1],
                li1z = l1v[(ni0 + 1) * 3 + 2];
    const float s00 = l0v[ni0], s01 = l0v[ni0 + 1];

    // t9 accumulators packed along l: tA?[lp] = (t9[2lp], t9[2lp+1]); t8 = t9[8]
    v2f tA0[4], tA1[4];
    float t80, t81;
#pragma unroll
    for (int lp = 0; lp < 4; lp++) {
        v2f tb = { vvb2[2 * lp] + vrb2[2 * lp] + sb2[2 * lp],
                   vvb2[2 * lp + 1] + vrb2[2 * lp + 1] + sb2[2 * lp + 1] };
        tA0[lp] = tb; tA1[lp] = tb;
    }
    t80 = t81 = vvb2[8] + vrb2[8] + sb2[8];

#pragma unroll
    for (int h = 0; h < 30; h++) {
        const float4 w0 = *(const float4*)&Pj[h * 8 + 0];
        const float4 w1 = *(const float4*)&Pj[h * 8 + 4];
        const float bv = vvb1[h], br = vrb1[h], sw = sW1[h];
        const u64 wv0 = ldw2(vvW2 + h * 9 + 0), wv1 = ldw2(vvW2 + h * 9 + 2);
        const u64 wv2 = ldw2(vvW2 + h * 9 + 4), wv3 = ldw2(vvW2 + h * 9 + 6);
        const u64 wr0 = ldw2(vrW2 + h * 9 + 0), wr1 = ldw2(vrW2 + h * 9 + 2);
        const u64 wr2 = ldw2(vrW2 + h * 9 + 4), wr3 = ldw2(vrW2 + h * 9 + 6);
        const u64 ws0 = ldw2(sW2 + h * 9 + 0),  ws1 = ldw2(sW2 + h * 9 + 2);
        const u64 ws2 = ldw2(sW2 + h * 9 + 4),  ws3 = ldw2(sW2 + h * 9 + 6);
        const float wv8 = vvW2[h * 9 + 8], wr8 = vrW2[h * 9 + 8], ws8 = sW2[h * 9 + 8];

        const float av0 = silu_f(w0.x * li0x + w0.y * li0y + w0.z * li0z + bv);
        const float ar0 = silu_f(w0.w * li0x + w1.x * li0y + w1.y * li0z + br);
        const float as0 = silu_f(w1.z + s00 * sw);
        const float av1 = silu_f(w0.x * li1x + w0.y * li1y + w0.z * li1z + bv);
        const float ar1 = silu_f(w0.w * li1x + w1.x * li1y + w1.y * li1z + br);
        const float as1 = silu_f(w1.z + s01 * sw);
        const v2f avp = { av0, av1 }, arp = { ar0, ar1 }, asp = { as0, as1 };

        pkfma_lo(tA0[0], avp, wv0); pkfma_lo(tA0[0], arp, wr0); pkfma_lo(tA0[0], asp, ws0);
        pkfma_lo(tA0[1], avp, wv1); pkfma_lo(tA0[1], arp, wr1); pkfma_lo(tA0[1], asp, ws1);
        pkfma_lo(tA0[2], avp, wv2); pkfma_lo(tA0[2], arp, wr2); pkfma_lo(tA0[2], asp, ws2);
        pkfma_lo(tA0[3], avp, wv3); pkfma_lo(tA0[3], arp, wr3); pkfma_lo(tA0[3], asp, ws3);
        pkfma_hi(tA1[0], avp, wv0); pkfma_hi(tA1[0], arp, wr0); pkfma_hi(tA1[0], asp, ws0);
        pkfma_hi(tA1[1], avp, wv1); pkfma_hi(tA1[1], arp, wr1); pkfma_hi(tA1[1], asp, ws1);
        pkfma_hi(tA1[2], avp, wv2); pkfma_hi(tA1[2], arp, wr2); pkfma_hi(tA1[2], asp, ws2);
        pkfma_hi(tA1[3], avp, wv3); pkfma_hi(tA1[3], arp, wr3); pkfma_hi(tA1[3], asp, ws3);
        t80 += av0 * wv8 + ar0 * wr8 + as0 * ws8;
        t81 += av1 * wv8 + ar1 * wr8 + as1 * ws8;
    }

    // ---- h-MLP 9->30->9, h processed in pairs; o packed along l -------------
    v2f oA0[4], oA1[4];
    float o80, o81;
#pragma unroll
    for (int lp = 0; lp < 4; lp++) {
        v2f ob = { hb2[2 * lp], hb2[2 * lp + 1] };
        oA0[lp] = ob; oA1[lp] = ob;
    }
    o80 = o81 = hb2[8];

    const v2f t8p0 = { t80, t80 }, t8p1 = { t81, t81 };

#pragma unroll
    for (int hp = 0; hp < 15; hp++) {
        const int h0 = 2 * hp, h1 = 2 * hp + 1;
        v2f a0 = { hb1[h0], hb1[h1] };
        v2f a1 = a0;
#pragma unroll
        for (int lp = 0; lp < 4; lp++) {
            const u64 wm0 = ldw2(hW1 + (2 * lp) * 30 + h0);
            const u64 wm1 = ldw2(hW1 + (2 * lp + 1) * 30 + h0);
            pkfma_lo(a0, tA0[lp], wm0); pkfma_hi(a0, tA0[lp], wm1);
            pkfma_lo(a1, tA1[lp], wm0); pkfma_hi(a1, tA1[lp], wm1);
        }
        const u64 w8 = ldw2(hW1 + 8 * 30 + h0);
        pkfma(a0, t8p0, w8);
        pkfma(a1, t8p1, w8);

        const float sx0 = silu_f(a0.x), sy0 = silu_f(a0.y);
        const float sx1 = silu_f(a1.x), sy1 = silu_f(a1.y);
        const v2f sp0 = { sx0, sy0 }, sp1 = { sx1, sy1 };

#pragma unroll
        for (int lp = 0; lp < 4; lp++) {
            const u64 u0 = ldw2(hW2 + h0 * 9 + 2 * lp);
            const u64 u1 = ldw2(hW2 + h1 * 9 + 2 * lp);
            pkfma_lo(oA0[lp], sp0, u0); pkfma_hi(oA0[lp], sp0, u1);
            pkfma_lo(oA1[lp], sp1, u0); pkfma_hi(oA1[lp], sp1, u1);
        }
        const float z0 = hW2[h0 * 9 + 8], z1 = hW2[h1 * 9 + 8];
        o80 += sx0 * z0 + sy0 * z1;
        o81 += sx1 * z0 + sy1 * z1;
    }

    // out[((b*A+i)*3+k)*288 + j*3 + l]
    float q0[9] = { oA0[0].x, oA0[0].y, oA0[1].x, oA0[1].y,
                    oA0[2].x, oA0[2].y, oA0[3].x, oA0[3].y, o80 };
    float q1[9] = { oA1[0].x, oA1[0].y, oA1[1].x, oA1[1].y,
                    oA1[2].x, oA1[2].y, oA1[3].x, oA1[3].y, o81 };
#pragma unroll
    for (int k = 0; k < 3; k++) {
        const size_t base0 = ((size_t)ni0 * 3 + k) * 288 + (size_t)j * 3;
        out[base0 + 0] = q0[3 * k + 0];
        out[base0 + 1] = q0[3 * k + 1];
        out[base0 + 2] = q0[3 * k + 2];
        const size_t base1 = base0 + 3 * 288;
        out[base1 + 0] = q1[3 * k + 0];
        out[base1 + 1] = q1[3 * k + 1];
        out[base1 + 2] = q1[3 * k + 2];
    }
}

extern "C" void kernel_launch(void* const* d_in, const int* in_sizes, int n_in,
                              void* d_out, int out_size, void* d_ws, size_t ws_size,
                              hipStream_t stream) {
    const float* pos   = (const float*)d_in[0];
    const float* srep  = (const float*)d_in[1];
    const float* vrep  = (const float*)d_in[2];
    const float* mixW1 = (const float*)d_in[3];
    const float* sc1W1 = (const float*)d_in[4];
    const float* sc1b1 = (const float*)d_in[5];
    const float* sc1W2 = (const float*)d_in[6];
    const float* sc1b2 = (const float*)d_in[7];
    const float* mixW2 = (const float*)d_in[8];
    const float* sc2W1 = (const float*)d_in[9];
    const float* sc2b1 = (const float*)d_in[10];
    const float* sc2W2 = (const float*)d_in[11];
    const float* sc2b2 = (const float*)d_in[12];
    const float* vvW1  = (const float*)d_in[13];
    const float* vvb1  = (const float*)d_in[14];
    const float* vvW2  = (const float*)d_in[15];
    const float* vvb2  = (const float*)d_in[16];
    const float* vrW1  = (const float*)d_in[17];
    const float* vrb1  = (const float*)d_in[18];
    const float* vrW2  = (const float*)d_in[19];
    const float* vrb2  = (const float*)d_in[20];
    const float* sW1   = (const float*)d_in[21];
    const float* sb1   = (const float*)d_in[22];
    const float* sW2   = (const float*)d_in[23];
    const float* sb2   = (const float*)d_in[24];
    const float* hW1   = (const float*)d_in[25];
    const float* hb1   = (const float*)d_in[26];
    const float* hW2   = (const float*)d_in[27];
    const float* hb2   = (const float*)d_in[28];

    float* ws  = (float*)d_ws;
    float* P   = ws;                               // PSTR*NNODES floats
    float* l0v = P + (size_t)PSTR * NNODES;        // 12,288
    float* l1v = l0v + NNODES;                     // 36,864
    float* outf = (float*)d_out;

    // 1. fused node stage -> l0, l1, P
    node_k<<<NNODES / NB, 128, 0, stream>>>(
        vrep, mixW1, srep,
        sc1W1, sc1b1, sc1W2, sc1b2,
        mixW2, sc2W1, sc2b1, sc2W2, sc2b2,
        pos, vvW1, vrW1, sW1, sb1,
        l0v, l1v, P);

    // 2. pair stage (2 i per thread, packed v_pk_fma_f32, full unroll)
    pair_k<<<dim3(A_ATOMS / 4, BATCH), 192, 0, stream>>>(
        l0v, l1v, P,
        vvb1, vrb1, sW1,
        vvW2, vrW2, sW2,
        vvb2, vrb2, sb2,
        hW1, hb1, hW2, hb2,
        outf);
}

// Round 11
// 260.697 us; speedup vs baseline: 1.0061x; 1.0061x over previous
//
#include <hip/hip_runtime.h>
#include <cstddef>

#define A_ATOMS 96
#define BATCH   128
#define NNODES  12288   // B*A
#define NB      8       // nodes per block (node_k)
#define AS      132     // AsL / workS stride (132%32=4)
#define XS      196     // xinS stride (196%32=4)
#define PSTR    240     // P row stride per node: 30 h * 8 floats

typedef float v2f __attribute__((ext_vector_type(2)));
typedef unsigned long long u64;

__device__ __forceinline__ float silu_f(float x) {
    float e = __expf(-x);
    return x * __builtin_amdgcn_rcpf(1.0f + e);
}

// ---- packed f32 FMA (CDNA VOP3P, full-rate 2xFMA): acc = a*w + acc ---------
// Weight pair w lives in a VGPR pair (loaded from LDS -> in-order lgkmcnt).
// _lo/_hi broadcast the low/high half of `a` to both lanes via op_sel.
__device__ __forceinline__ void pkfma(v2f& acc, v2f a, u64 w) {
    asm("v_pk_fma_f32 %0, %1, %2, %0" : "+v"(acc) : "v"(a), "v"(w));
}
__device__ __forceinline__ void pkfma_lo(v2f& acc, v2f a, u64 w) {
    asm("v_pk_fma_f32 %0, %1, %2, %0 op_sel:[0,0,0] op_sel_hi:[0,1,1]"
        : "+v"(acc) : "v"(a), "v"(w));
}
__device__ __forceinline__ void pkfma_hi(v2f& acc, v2f a, u64 w) {
    asm("v_pk_fma_f32 %0, %1, %2, %0 op_sel:[1,0,0] op_sel_hi:[1,1,1]"
        : "+v"(acc) : "v"(a), "v"(w));
}
__device__ __forceinline__ u64 ldw2(const float* p) {
    u64 w; __builtin_memcpy(&w, p, 8); return w;   // 8B-aligned pair load
}

#define RED64(v) { v += __shfl_xor(v, 1); v += __shfl_xor(v, 2); v += __shfl_xor(v, 4); \
                   v += __shfl_xor(v, 8); v += __shfl_xor(v, 16); v += __shfl_xor(v, 32); }
#define RED16(v) { v += __shfl_xor(v, 1); v += __shfl_xor(v, 2); v += __shfl_xor(v, 4); \
                   v += __shfl_xor(v, 8); }

// ===== fused node kernel: R9 version verbatim (R2 body + P-emit tail) =======
__global__ __launch_bounds__(128, 3)
void node_k(const float* __restrict__ vrep, const float* __restrict__ mixW1,
            const float* __restrict__ srep,
            const float* __restrict__ sc1W1, const float* __restrict__ sc1b1,
            const float* __restrict__ sc1W2, const float* __restrict__ sc1b2,
            const float* __restrict__ mixW2,
            const float* __restrict__ sc2W1, const float* __restrict__ sc2b1,
            const float* __restrict__ sc2W2, const float* __restrict__ sc2b2,
            const float* __restrict__ pos,
            const float* __restrict__ vvW1, const float* __restrict__ vrW1,
            const float* __restrict__ sW1,  const float* __restrict__ sb1,
            float* __restrict__ l0v, float* __restrict__ l1v,
            float* __restrict__ P) {
    __shared__ float AsL[24 * AS];
    __shared__ float xinS[NB * XS];
    __shared__ float s1s[2][4][64];
    __shared__ float pwp[NB][6];
    __shared__ float gateS[NB], l0S[NB];

    const int t  = threadIdx.x;
    const int w  = t >> 6;
    const int ln = t & 63;
    const int cx = ln & 15;
    const int ry = ln >> 4;
    const int cb = w * 64 + cx * 4;
    const int row0  = blockIdx.x * 24;
    const int node0 = blockIdx.x * NB;

#pragma unroll
    for (int it = 0; it < 6; it++) {
        const int idx = it * 128 + t;
        const int r   = idx >> 5;
        const int c4  = (idx & 31) * 4;
        *(float4*)&AsL[r * AS + c4] = *(const float4*)(vrep + (size_t)(row0 + r) * 128 + c4);
    }
#pragma unroll
    for (int it = 0; it < 2; it++) {
        const int idx = it * 128 + t;
        const int a   = idx >> 5;
        const int c4  = (idx & 31) * 4;
        *(float4*)&xinS[a * XS + c4] = *(const float4*)(srep + (size_t)(node0 + a) * 128 + c4);
    }
    __syncthreads();

    float acc[2][3][4];
#pragma unroll
    for (int p = 0; p < 2; p++)
#pragma unroll
        for (int d = 0; d < 3; d++)
#pragma unroll
            for (int j = 0; j < 4; j++) acc[p][d][j] = 0.0f;

    for (int kc = 0; kc < 128; kc += 8) {
        float a[2][3][8];
#pragma unroll
        for (int p = 0; p < 2; p++)
#pragma unroll
            for (int d = 0; d < 3; d++) {
                const int row = (3 * (ry + 4 * p) + d) * AS + kc;
                *(float4*)&a[p][d][0] = *(const float4*)&AsL[row];
                *(float4*)&a[p][d][4] = *(const float4*)&AsL[row + 4];
            }
#pragma unroll
        for (int kk = 0; kk < 8; kk++) {
            float b[4];
            *(float4*)b = *(const float4*)(mixW1 + (size_t)(kc + kk) * 128 + cb);
#pragma unroll
            for (int p = 0; p < 2; p++)
#pragma unroll
                for (int d = 0; d < 3; d++)
#pragma unroll
                    for (int j = 0; j < 4; j++)
                        acc[p][d][j] += a[p][d][kk] * b[j];
        }
    }
    if (w == 0) {
#pragma unroll
        for (int p = 0; p < 2; p++) {
            float nrm[4];
#pragma unroll
            for (int c = 0; c < 4; c++)
                nrm[c] = sqrtf(acc[p][0][c] * acc[p][0][c] + acc[p][1][c] * acc[p][1][c]
                             + acc[p][2][c] * acc[p][2][c]);
            *(float4*)&xinS[(ry + 4 * p) * XS + 128 + cb] = *(float4*)nrm;
        }
    }
    __syncthreads();

    float* workS = AsL;
    {
        float acc3[2][4];
#pragma unroll
        for (int p = 0; p < 2; p++)
#pragma unroll
            for (int j = 0; j < 4; j++) acc3[p][j] = 0.0f;
        for (int kc = 0; kc < 192; kc += 8) {
            float af[2][8];
#pragma unroll
            for (int p = 0; p < 2; p++) {
                const int row = (ry + 4 * p) * XS + kc;
                *(float4*)&af[p][0] = *(const float4*)&xinS[row];
                *(float4*)&af[p][4] = *(const float4*)&xinS[row + 4];
            }
#pragma unroll
            for (int kk = 0; kk < 8; kk++) {
                float b[4];
                *(float4*)b = *(const float4*)(sc1W1 + (size_t)(kc + kk) * 128 + cb);
#pragma unroll
                for (int p = 0; p < 2; p++)
#pragma unroll
                    for (int j = 0; j < 4; j++) acc3[p][j] += af[p][kk] * b[j];
            }
        }
#pragma unroll
        for (int p = 0; p < 2; p++) {
            float h[4];
#pragma unroll
            for (int j = 0; j < 4; j++) h[j] = silu_f(acc3[p][j] + sc1b1[cb + j]);
            *(float4*)&workS[(ry + 4 * p) * AS + cb] = *(float4*)h;
        }
    }
    __syncthreads();

    float xg[2][4];
    {
        float acc4[2][4];
#pragma unroll
        for (int p = 0; p < 2; p++)
#pragma unroll
            for (int j = 0; j < 4; j++) acc4[p][j] = 0.0f;
        for (int kc = 0; kc < 128; kc += 8) {
            float af[2][8];
#pragma unroll
            for (int p = 0; p < 2; p++) {
                const int row = (ry + 4 * p) * AS + kc;
                *(float4*)&af[p][0] = *(const float4*)&workS[row];
                *(float4*)&af[p][4] = *(const float4*)&workS[row + 4];
            }
#pragma unroll
            for (int kk = 0; kk < 8; kk++) {
                float b[4];
                *(float4*)b = *(const float4*)(sc1W2 + (size_t)(kc + kk) * 128 + cb);
#pragma unroll
                for (int p = 0; p < 2; p++)
#pragma unroll
                    for (int j = 0; j < 4; j++) acc4[p][j] += af[p][kk] * b[j];
            }
        }
        if (w == 0) {
#pragma unroll
            for (int p = 0; p < 2; p++) {
                float xs[4];
#pragma unroll
                for (int j = 0; j < 4; j++) xs[j] = acc4[p][j] + sc1b2[cb + j];
                *(float4*)&xinS[(ry + 4 * p) * XS + cb] = *(float4*)xs;
            }
        } else {
#pragma unroll
            for (int p = 0; p < 2; p++)
#pragma unroll
                for (int j = 0; j < 4; j++) xg[p][j] = acc4[p][j] + sc1b2[cb + j];
        }
    }

    if (w == 1) {
#pragma unroll
        for (int p = 0; p < 2; p++) {
            float p0 = 0, p1 = 0, p2 = 0, p3 = 0, p4 = 0, p5 = 0;
#pragma unroll
            for (int c = 0; c < 4; c++) {
                float2 m = *(const float2*)(mixW2 + (size_t)(cb - 64 + c) * 2);
                const float v0 = xg[p][c] * acc[p][0][c];
                const float v1 = xg[p][c] * acc[p][1][c];
                const float v2 = xg[p][c] * acc[p][2][c];
                p0 += v0 * m.x; p1 += v0 * m.y;
                p2 += v1 * m.x; p3 += v1 * m.y;
                p4 += v2 * m.x; p5 += v2 * m.y;
            }
            RED16(p0); RED16(p1); RED16(p2); RED16(p3); RED16(p4); RED16(p5);
            if (cx == 0) {
                const int nl = ry + 4 * p;
                pwp[nl][0] = p0; pwp[nl][1] = p1;
                pwp[nl][2] = p2; pwp[nl][3] = p3;
                pwp[nl][4] = p4; pwp[nl][5] = p5;
            }
        }
    }
    __syncthreads();

    {
        const float bb1 = sc2b1[ln];
        const float wn  = sc2W1[64 * 64 + ln];
        const float wq0 = sc2W2[ln * 2 + 0], wq1 = sc2W2[ln * 2 + 1];
        float vn2[4], g0[4], g1[4], g2[4];
#pragma unroll
        for (int r = 0; r < 4; r++) {
            const int nl = r * 2 + w;
            const float q00 = pwp[nl][0], q10 = pwp[nl][2], q20 = pwp[nl][4];
            vn2[r] = sqrtf(q00 * q00 + q10 * q10 + q20 * q20);
            g0[r] = pwp[nl][1]; g1[r] = pwp[nl][3]; g2[r] = pwp[nl][5];
            s1s[w][r][ln] = silu_f(xinS[nl * XS + ln]);
        }
        __builtin_amdgcn_s_waitcnt(0);
        float acc5[4];
#pragma unroll
        for (int r = 0; r < 4; r++) acc5[r] = bb1 + vn2[r] * wn;
#pragma unroll 8
        for (int i2 = 0; i2 < 64; i2++) {
            const float wv = sc2W1[i2 * 64 + ln];
#pragma unroll
            for (int r = 0; r < 4; r++) acc5[r] += s1s[w][r][i2] * wv;
        }
#pragma unroll
        for (int r = 0; r < 4; r++) {
            const float h2 = silu_f(acc5[r]);
            float q0 = h2 * wq0, q1 = h2 * wq1;
            RED64(q0); RED64(q1);
            if (ln == 0) {
                const int nl = r * 2 + w;
                const int n = node0 + nl;
                const float gate = q1 + sc2b2[1];
                const float l0o  = q0 + sc2b2[0];
                l0v[n] = l0o;
                l1v[(size_t)n * 3 + 0] = gate * g0[r];
                l1v[(size_t)n * 3 + 1] = gate * g1[r];
                l1v[(size_t)n * 3 + 2] = gate * g2[r];
                gateS[nl] = gate;
                l0S[nl]   = l0o;
            }
        }
    }
    __syncthreads();

    // P-emit tail: layout [node][h<30][8] = {pv0,pv1,pv2,pr0,pr1,pr2,ps,0}
    {
        const int nl = t >> 4;          // 0..7
        const int q  = t & 15;          // 0..15
        const int n  = node0 + nl;
        const float lj0 = gateS[nl] * pwp[nl][1];
        const float lj1 = gateS[nl] * pwp[nl][3];
        const float lj2 = gateS[nl] * pwp[nl][5];
        const float l0j = l0S[nl];
        const float pj0 = pos[n * 3 + 0], pj1 = pos[n * 3 + 1], pj2 = pos[n * 3 + 2];
        float* Pj = P + (size_t)n * PSTR;
        for (int h = q; h < 30; h += 16) {
            float o[8];
#pragma unroll
            for (int a = 0; a < 3; a++) {
                o[a]     = lj0 * vvW1[(3 * a + 0) * 30 + h]
                         + lj1 * vvW1[(3 * a + 1) * 30 + h]
                         + lj2 * vvW1[(3 * a + 2) * 30 + h];
                o[3 + a] = pj0 * vrW1[(3 * a + 0) * 30 + h]
                         + pj1 * vrW1[(3 * a + 1) * 30 + h]
                         + pj2 * vrW1[(3 * a + 2) * 30 + h];
            }
            o[6] = sb1[h] + l0j * sW1[30 + h];
            o[7] = 0.0f;
            *(float4*)&Pj[h * 8 + 0] = *(float4*)&o[0];
            *(float4*)&Pj[h * 8 + 4] = *(float4*)&o[4];
        }
    }
}

// ---------- pair kernel v9: R9 schedule, weights staged in LDS --------------
// SMEM (s_load) completes out-of-order -> any use forces lgkmcnt(0), draining
// ALL scalar loads each iteration (the theorized 33% stall). DS ops complete
// IN-ORDER -> precise lgkmcnt(N) waits, weight reads pipeline across h.
// Rows padded to 10 floats so every 64-bit ds_read is 8B-aligned.
__global__ __launch_bounds__(192)
void pair_k(const float* __restrict__ l0v, const float* __restrict__ l1v,
            const float* __restrict__ P,
            const float* __restrict__ vvb1, const float* __restrict__ vrb1,
            const float* __restrict__ sW1,
            const float* __restrict__ vvW2, const float* __restrict__ vrW2,
            const float* __restrict__ sW2,
            const float* __restrict__ vvb2, const float* __restrict__ vrb2,
            const float* __restrict__ sb2,
            const float* __restrict__ hW1,  const float* __restrict__ hb1,
            const float* __restrict__ hW2,  const float* __restrict__ hb2,
            float* __restrict__ out) {
    __shared__ __align__(16) float wvS[300];   // vvW2 [h][l], row stride 10
    __shared__ __align__(16) float wrS[300];   // vrW2
    __shared__ __align__(16) float wsS[300];   // sW2
    __shared__ __align__(16) float h1S[270];   // hW1 [m*30+h] (unpadded: pairs along h)
    __shared__ __align__(16) float h2S[300];   // hW2 [h][l], row stride 10
    __shared__ __align__(16) float bS[120];    // [0..29]=vvb1 [30..59]=vrb1 [60..89]=sW1 [90..119]=hb1

    const int t = threadIdx.x;
    for (int i = t; i < 270; i += 192) {
        const int r = (i / 9) * 10 + (i % 9);
        wvS[r] = vvW2[i];
        wrS[r] = vrW2[i];
        wsS[r] = sW2[i];
        h2S[r] = hW2[i];
        h1S[i] = hW1[i];
    }
    if (t < 30) {
        bS[t]      = vvb1[t];
        bS[30 + t] = vrb1[t];
        bS[60 + t] = sW1[t];
        bS[90 + t] = hb1[t];
    }
    __syncthreads();

    const int b = blockIdx.y;
    const int g = (t >= 96) ? 1 : 0;
    const int j = t - g * 96;
    const int i0 = blockIdx.x * 4 + g * 2;
    const int ni0 = b * A_ATOMS + i0;       // thread: i = ni0, ni0+1
    const int nj  = b * A_ATOMS + j;
    const float* Pj = P + (size_t)nj * PSTR;

    const float li0x = l1v[ni0 * 3 + 0], li0y = l1v[ni0 * 3 + 1], li0z = l1v[ni0 * 3 + 2];
    const float li1x = l1v[(ni0 + 1) * 3 + 0], li1y = l1v[(ni0 + 1) * 3 + 1],
                li1z = l1v[(ni0 + 1) * 3 + 2];
    const float s00 = l0v[ni0], s01 = l0v[ni0 + 1];

    // t9 accumulators packed along l: tA?[lp] = (t9[2lp], t9[2lp+1]); t8 = t9[8]
    v2f tA0[4], tA1[4];
    float t80, t81;
#pragma unroll
    for (int lp = 0; lp < 4; lp++) {
        v2f tb = { vvb2[2 * lp] + vrb2[2 * lp] + sb2[2 * lp],
                   vvb2[2 * lp + 1] + vrb2[2 * lp + 1] + sb2[2 * lp + 1] };
        tA0[lp] = tb; tA1[lp] = tb;
    }
    t80 = t81 = vvb2[8] + vrb2[8] + sb2[8];

#pragma unroll 2
    for (int h = 0; h < 30; h++) {
        const float4 w0 = *(const float4*)&Pj[h * 8 + 0];
        const float4 w1 = *(const float4*)&Pj[h * 8 + 4];
        const float bv = bS[h], br = bS[30 + h], sw = bS[60 + h];
        const float* vr_ = &wvS[h * 10];
        const float* rr_ = &wrS[h * 10];
        const float* sr_ = &wsS[h * 10];
        const u64 wv0 = ldw2(vr_ + 0), wv1 = ldw2(vr_ + 2);
        const u64 wv2 = ldw2(vr_ + 4), wv3 = ldw2(vr_ + 6);
        const u64 wr0 = ldw2(rr_ + 0), wr1 = ldw2(rr_ + 2);
        const u64 wr2 = ldw2(rr_ + 4), wr3 = ldw2(rr_ + 6);
        const u64 ws0 = ldw2(sr_ + 0), ws1 = ldw2(sr_ + 2);
        const u64 ws2 = ldw2(sr_ + 4), ws3 = ldw2(sr_ + 6);
        const float wv8 = vr_[8], wr8 = rr_[8], ws8 = sr_[8];

        const float av0 = silu_f(w0.x * li0x + w0.y * li0y + w0.z * li0z + bv);
        const float ar0 = silu_f(w0.w * li0x + w1.x * li0y + w1.y * li0z + br);
        const float as0 = silu_f(w1.z + s00 * sw);
        const float av1 = silu_f(w0.x * li1x + w0.y * li1y + w0.z * li1z + bv);
        const float ar1 = silu_f(w0.w * li1x + w1.x * li1y + w1.y * li1z + br);
        const float as1 = silu_f(w1.z + s01 * sw);
        const v2f avp = { av0, av1 }, arp = { ar0, ar1 }, asp = { as0, as1 };

        pkfma_lo(tA0[0], avp, wv0); pkfma_lo(tA0[0], arp, wr0); pkfma_lo(tA0[0], asp, ws0);
        pkfma_lo(tA0[1], avp, wv1); pkfma_lo(tA0[1], arp, wr1); pkfma_lo(tA0[1], asp, ws1);
        pkfma_lo(tA0[2], avp, wv2); pkfma_lo(tA0[2], arp, wr2); pkfma_lo(tA0[2], asp, ws2);
        pkfma_lo(tA0[3], avp, wv3); pkfma_lo(tA0[3], arp, wr3); pkfma_lo(tA0[3], asp, ws3);
        pkfma_hi(tA1[0], avp, wv0); pkfma_hi(tA1[0], arp, wr0); pkfma_hi(tA1[0], asp, ws0);
        pkfma_hi(tA1[1], avp, wv1); pkfma_hi(tA1[1], arp, wr1); pkfma_hi(tA1[1], asp, ws1);
        pkfma_hi(tA1[2], avp, wv2); pkfma_hi(tA1[2], arp, wr2); pkfma_hi(tA1[2], asp, ws2);
        pkfma_hi(tA1[3], avp, wv3); pkfma_hi(tA1[3], arp, wr3); pkfma_hi(tA1[3], asp, ws3);
        t80 += av0 * wv8 + ar0 * wr8 + as0 * ws8;
        t81 += av1 * wv8 + ar1 * wr8 + as1 * ws8;
    }

    // ---- h-MLP 9->30->9, h processed in pairs; o packed along l -------------
    v2f oA0[4], oA1[4];
    float o80, o81;
#pragma unroll
    for (int lp = 0; lp < 4; lp++) {
        v2f ob = { hb2[2 * lp], hb2[2 * lp + 1] };
        oA0[lp] = ob; oA1[lp] = ob;
    }
    o80 = o81 = hb2[8];

    const v2f t8p0 = { t80, t80 }, t8p1 = { t81, t81 };

#pragma unroll 3
    for (int hp = 0; hp < 15; hp++) {
        const int h0 = 2 * hp, h1 = 2 * hp + 1;
        v2f a0 = { bS[90 + h0], bS[90 + h1] };
        v2f a1 = a0;
#pragma unroll
        for (int lp = 0; lp < 4; lp++) {
            const u64 wm0 = ldw2(&h1S[(2 * lp) * 30 + h0]);
            const u64 wm1 = ldw2(&h1S[(2 * lp + 1) * 30 + h0]);
            pkfma_lo(a0, tA0[lp], wm0); pkfma_hi(a0, tA0[lp], wm1);
            pkfma_lo(a1, tA1[lp], wm0); pkfma_hi(a1, tA1[lp], wm1);
        }
        const u64 w8 = ldw2(&h1S[8 * 30 + h0]);
        pkfma(a0, t8p0, w8);
        pkfma(a1, t8p1, w8);

        const float sx0 = silu_f(a0.x), sy0 = silu_f(a0.y);
        const float sx1 = silu_f(a1.x), sy1 = silu_f(a1.y);
        const v2f sp0 = { sx0, sy0 }, sp1 = { sx1, sy1 };

#pragma unroll
        for (int lp = 0; lp < 4; lp++) {
            const u64 u0 = ldw2(&h2S[h0 * 10 + 2 * lp]);
            const u64 u1 = ldw2(&h2S[h1 * 10 + 2 * lp]);
            pkfma_lo(oA0[lp], sp0, u0); pkfma_hi(oA0[lp], sp0, u1);
            pkfma_lo(oA1[lp], sp1, u0); pkfma_hi(oA1[lp], sp1, u1);
        }
        const float z0 = h2S[h0 * 10 + 8], z1 = h2S[h1 * 10 + 8];
        o80 += sx0 * z0 + sy0 * z1;
        o81 += sx1 * z0 + sy1 * z1;
    }

    // out[((b*A+i)*3+k)*288 + j*3 + l]
    float q0[9] = { oA0[0].x, oA0[0].y, oA0[1].x, oA0[1].y,
                    oA0[2].x, oA0[2].y, oA0[3].x, oA0[3].y, o80 };
    float q1[9] = { oA1[0].x, oA1[0].y, oA1[1].x, oA1[1].y,
                    oA1[2].x, oA1[2].y, oA1[3].x, oA1[3].y, o81 };
#pragma unroll
    for (int k = 0; k < 3; k++) {
        const size_t base0 = ((size_t)ni0 * 3 + k) * 288 + (size_t)j * 3;
        out[base0 + 0] = q0[3 * k + 0];
        out[base0 + 1] = q0[3 * k + 1];
        out[base0 + 2] = q0[3 * k + 2];
        const size_t base1 = base0 + 3 * 288;
        out[base1 + 0] = q1[3 * k + 0];
        out[base1 + 1] = q1[3 * k + 1];
        out[base1 + 2] = q1[3 * k + 2];
    }
}

extern "C" void kernel_launch(void* const* d_in, const int* in_sizes, int n_in,
                              void* d_out, int out_size, void* d_ws, size_t ws_size,
                              hipStream_t stream) {
    const float* pos   = (const float*)d_in[0];
    const float* srep  = (const float*)d_in[1];
    const float* vrep  = (const float*)d_in[2];
    const float* mixW1 = (const float*)d_in[3];
    const float* sc1W1 = (const float*)d_in[4];
    const float* sc1b1 = (const float*)d_in[5];
    const float* sc1W2 = (const float*)d_in[6];
    const float* sc1b2 = (const float*)d_in[7];
    const float* mixW2 = (const float*)d_in[8];
    const float* sc2W1 = (const float*)d_in[9];
    const float* sc2b1 = (const float*)d_in[10];
    const float* sc2W2 = (const float*)d_in[11];
    const float* sc2b2 = (const float*)d_in[12];
    const float* vvW1  = (const float*)d_in[13];
    const float* vvb1  = (const float*)d_in[14];
    const float* vvW2  = (const float*)d_in[15];
    const float* vvb2  = (const float*)d_in[16];
    const float* vrW1  = (const float*)d_in[17];
    const float* vrb1  = (const float*)d_in[18];
    const float* vrW2  = (const float*)d_in[19];
    const float* vrb2  = (const float*)d_in[20];
    const float* sW1   = (const float*)d_in[21];
    const float* sb1   = (const float*)d_in[22];
    const float* sW2   = (const float*)d_in[23];
    const float* sb2   = (const float*)d_in[24];
    const float* hW1   = (const float*)d_in[25];
    const float* hb1   = (const float*)d_in[26];
    const float* hW2   = (const float*)d_in[27];
    const float* hb2   = (const float*)d_in[28];

    float* ws  = (float*)d_ws;
    float* P   = ws;                               // PSTR*NNODES floats
    float* l0v = P + (size_t)PSTR * NNODES;        // 12,288
    float* l1v = l0v + NNODES;                     // 36,864
    float* outf = (float*)d_out;

    // 1. fused node stage -> l0, l1, P
    node_k<<<NNODES / NB, 128, 0, stream>>>(
        vrep, mixW1, srep,
        sc1W1, sc1b1, sc1W2, sc1b2,
        mixW2, sc2W1, sc2b1, sc2W2, sc2b2,
        pos, vvW1, vrW1, sW1, sb1,
        l0v, l1v, P);

    // 2. pair stage (2 i per thread, pk_fma, LDS-staged weights)
    pair_k<<<dim3(A_ATOMS / 4, BATCH), 192, 0, stream>>>(
        l0v, l1v, P,
        vvb1, vrb1, sW1,
        vvW2, vrW2, sW2,
        vvb2, vrb2, sb2,
        hW1, hb1, hW2, hb2,
        outf);
}

// Round 12
// 252.166 us; speedup vs baseline: 1.0402x; 1.0338x over previous
//
#include <hip/hip_runtime.h>
#include <cstddef>

#define A_ATOMS 96
#define BATCH   128
#define NNODES  12288   // B*A
#define NB      8       // nodes per block (node_k)
#define AS      132     // AsL / workS stride (132%32=4)
#define XS      196     // xinS stride (196%32=4)
#define PSTR    240     // P row stride per node: 30 h * 8 floats

typedef float v2f __attribute__((ext_vector_type(2)));
typedef unsigned long long u64;

__device__ __forceinline__ float silu_f(float x) {
    float e = __expf(-x);
    return x * __builtin_amdgcn_rcpf(1.0f + e);
}

// ---- packed f32 FMA (CDNA VOP3P, full-rate 2xFMA): acc = a*w + acc ---------
// w is a wave-uniform 64-bit weight pair -> SGPR operand (1 const-bus slot).
// _lo/_hi broadcast the low/high half of `a` to both lanes via op_sel.
__device__ __forceinline__ void pkfma(v2f& acc, v2f a, u64 w) {
    asm("v_pk_fma_f32 %0, %1, %2, %0" : "+v"(acc) : "v"(a), "s"(w));
}
__device__ __forceinline__ void pkfma_lo(v2f& acc, v2f a, u64 w) {
    asm("v_pk_fma_f32 %0, %1, %2, %0 op_sel:[0,0,0] op_sel_hi:[0,1,1]"
        : "+v"(acc) : "v"(a), "s"(w));
}
__device__ __forceinline__ void pkfma_hi(v2f& acc, v2f a, u64 w) {
    asm("v_pk_fma_f32 %0, %1, %2, %0 op_sel:[1,0,0] op_sel_hi:[1,1,1]"
        : "+v"(acc) : "v"(a), "s"(w));
}
__device__ __forceinline__ u64 ldw2(const float* p) {
    u64 w; __builtin_memcpy(&w, p, 8); return w;   // 4B-aligned-safe pair load
}

#define RED64(v) { v += __shfl_xor(v, 1); v += __shfl_xor(v, 2); v += __shfl_xor(v, 4); \
                   v += __shfl_xor(v, 8); v += __shfl_xor(v, 16); v += __shfl_xor(v, 32); }
#define RED16(v) { v += __shfl_xor(v, 1); v += __shfl_xor(v, 2); v += __shfl_xor(v, 4); \
                   v += __shfl_xor(v, 8); }

// ===== fused node kernel: R7 version unchanged (R2 body + P-emit tail) ======
__global__ __launch_bounds__(128, 3)
void node_k(const float* __restrict__ vrep, const float* __restrict__ mixW1,
            const float* __restrict__ srep,
            const float* __restrict__ sc1W1, const float* __restrict__ sc1b1,
            const float* __restrict__ sc1W2, const float* __restrict__ sc1b2,
            const float* __restrict__ mixW2,
            const float* __restrict__ sc2W1, const float* __restrict__ sc2b1,
            const float* __restrict__ sc2W2, const float* __restrict__ sc2b2,
            const float* __restrict__ pos,
            const float* __restrict__ vvW1, const float* __restrict__ vrW1,
            const float* __restrict__ sW1,  const float* __restrict__ sb1,
            float* __restrict__ l0v, float* __restrict__ l1v,
            float* __restrict__ P) {
    __shared__ float AsL[24 * AS];
    __shared__ float xinS[NB * XS];
    __shared__ float s1s[2][4][64];
    __shared__ float pwp[NB][6];
    __shared__ float gateS[NB], l0S[NB];

    const int t  = threadIdx.x;
    const int w  = t >> 6;
    const int ln = t & 63;
    const int cx = ln & 15;
    const int ry = ln >> 4;
    const int cb = w * 64 + cx * 4;
    const int row0  = blockIdx.x * 24;
    const int node0 = blockIdx.x * NB;

#pragma unroll
    for (int it = 0; it < 6; it++) {
        const int idx = it * 128 + t;
        const int r   = idx >> 5;
        const int c4  = (idx & 31) * 4;
        *(float4*)&AsL[r * AS + c4] = *(const float4*)(vrep + (size_t)(row0 + r) * 128 + c4);
    }
#pragma unroll
    for (int it = 0; it < 2; it++) {
        const int idx = it * 128 + t;
        const int a   = idx >> 5;
        const int c4  = (idx & 31) * 4;
        *(float4*)&xinS[a * XS + c4] = *(const float4*)(srep + (size_t)(node0 + a) * 128 + c4);
    }
    __syncthreads();

    float acc[2][3][4];
#pragma unroll
    for (int p = 0; p < 2; p++)
#pragma unroll
        for (int d = 0; d < 3; d++)
#pragma unroll
            for (int j = 0; j < 4; j++) acc[p][d][j] = 0.0f;

    for (int kc = 0; kc < 128; kc += 8) {
        float a[2][3][8];
#pragma unroll
        for (int p = 0; p < 2; p++)
#pragma unroll
            for (int d = 0; d < 3; d++) {
                const int row = (3 * (ry + 4 * p) + d) * AS + kc;
                *(float4*)&a[p][d][0] = *(const float4*)&AsL[row];
                *(float4*)&a[p][d][4] = *(const float4*)&AsL[row + 4];
            }
#pragma unroll
        for (int kk = 0; kk < 8; kk++) {
            float b[4];
            *(float4*)b = *(const float4*)(mixW1 + (size_t)(kc + kk) * 128 + cb);
#pragma unroll
            for (int p = 0; p < 2; p++)
#pragma unroll
                for (int d = 0; d < 3; d++)
#pragma unroll
                    for (int j = 0; j < 4; j++)
                        acc[p][d][j] += a[p][d][kk] * b[j];
        }
    }
    if (w == 0) {
#pragma unroll
        for (int p = 0; p < 2; p++) {
            float nrm[4];
#pragma unroll
            for (int c = 0; c < 4; c++)
                nrm[c] = sqrtf(acc[p][0][c] * acc[p][0][c] + acc[p][1][c] * acc[p][1][c]
                             + acc[p][2][c] * acc[p][2][c]);
            *(float4*)&xinS[(ry + 4 * p) * XS + 128 + cb] = *(float4*)nrm;
        }
    }
    __syncthreads();

    float* workS = AsL;
    {
        float acc3[2][4];
#pragma unroll
        for (int p = 0; p < 2; p++)
#pragma unroll
            for (int j = 0; j < 4; j++) acc3[p][j] = 0.0f;
        for (int kc = 0; kc < 192; kc += 8) {
            float af[2][8];
#pragma unroll
            for (int p = 0; p < 2; p++) {
                const int row = (ry + 4 * p) * XS + kc;
                *(float4*)&af[p][0] = *(const float4*)&xinS[row];
                *(float4*)&af[p][4] = *(const float4*)&xinS[row + 4];
            }
#pragma unroll
            for (int kk = 0; kk < 8; kk++) {
                float b[4];
                *(float4*)b = *(const float4*)(sc1W1 + (size_t)(kc + kk) * 128 + cb);
#pragma unroll
                for (int p = 0; p < 2; p++)
#pragma unroll
                    for (int j = 0; j < 4; j++) acc3[p][j] += af[p][kk] * b[j];
            }
        }
#pragma unroll
        for (int p = 0; p < 2; p++) {
            float h[4];
#pragma unroll
            for (int j = 0; j < 4; j++) h[j] = silu_f(acc3[p][j] + sc1b1[cb + j]);
            *(float4*)&workS[(ry + 4 * p) * AS + cb] = *(float4*)h;
        }
    }
    __syncthreads();

    float xg[2][4];
    {
        float acc4[2][4];
#pragma unroll
        for (int p = 0; p < 2; p++)
#pragma unroll
            for (int j = 0; j < 4; j++) acc4[p][j] = 0.0f;
        for (int kc = 0; kc < 128; kc += 8) {
            float af[2][8];
#pragma unroll
            for (int p = 0; p < 2; p++) {
                const int row = (ry + 4 * p) * AS + kc;
                *(float4*)&af[p][0] = *(const float4*)&workS[row];
                *(float4*)&af[p][4] = *(const float4*)&workS[row + 4];
            }
#pragma unroll
            for (int kk = 0; kk < 8; kk++) {
                float b[4];
                *(float4*)b = *(const float4*)(sc1W2 + (size_t)(kc + kk) * 128 + cb);
#pragma unroll
                for (int p = 0; p < 2; p++)
#pragma unroll
                    for (int j = 0; j < 4; j++) acc4[p][j] += af[p][kk] * b[j];
            }
        }
        if (w == 0) {
#pragma unroll
            for (int p = 0; p < 2; p++) {
                float xs[4];
#pragma unroll
                for (int j = 0; j < 4; j++) xs[j] = acc4[p][j] + sc1b2[cb + j];
                *(float4*)&xinS[(ry + 4 * p) * XS + cb] = *(float4*)xs;
            }
        } else {
#pragma unroll
            for (int p = 0; p < 2; p++)
#pragma unroll
                for (int j = 0; j < 4; j++) xg[p][j] = acc4[p][j] + sc1b2[cb + j];
        }
    }

    if (w == 1) {
#pragma unroll
        for (int p = 0; p < 2; p++) {
            float p0 = 0, p1 = 0, p2 = 0, p3 = 0, p4 = 0, p5 = 0;
#pragma unroll
            for (int c = 0; c < 4; c++) {
                float2 m = *(const float2*)(mixW2 + (size_t)(cb - 64 + c) * 2);
                const float v0 = xg[p][c] * acc[p][0][c];
                const float v1 = xg[p][c] * acc[p][1][c];
                const float v2 = xg[p][c] * acc[p][2][c];
                p0 += v0 * m.x; p1 += v0 * m.y;
                p2 += v1 * m.x; p3 += v1 * m.y;
                p4 += v2 * m.x; p5 += v2 * m.y;
            }
            RED16(p0); RED16(p1); RED16(p2); RED16(p3); RED16(p4); RED16(p5);
            if (cx == 0) {
                const int nl = ry + 4 * p;
                pwp[nl][0] = p0; pwp[nl][1] = p1;
                pwp[nl][2] = p2; pwp[nl][3] = p3;
                pwp[nl][4] = p4; pwp[nl][5] = p5;
            }
        }
    }
    __syncthreads();

    {
        const float bb1 = sc2b1[ln];
        const float wn  = sc2W1[64 * 64 + ln];
        const float wq0 = sc2W2[ln * 2 + 0], wq1 = sc2W2[ln * 2 + 1];
        float vn2[4], g0[4], g1[4], g2[4];
#pragma unroll
        for (int r = 0; r < 4; r++) {
            const int nl = r * 2 + w;
            const float q00 = pwp[nl][0], q10 = pwp[nl][2], q20 = pwp[nl][4];
            vn2[r] = sqrtf(q00 * q00 + q10 * q10 + q20 * q20);
            g0[r] = pwp[nl][1]; g1[r] = pwp[nl][3]; g2[r] = pwp[nl][5];
            s1s[w][r][ln] = silu_f(xinS[nl * XS + ln]);
        }
        __builtin_amdgcn_s_waitcnt(0);
        float acc5[4];
#pragma unroll
        for (int r = 0; r < 4; r++) acc5[r] = bb1 + vn2[r] * wn;
#pragma unroll 8
        for (int i2 = 0; i2 < 64; i2++) {
            const float wv = sc2W1[i2 * 64 + ln];
#pragma unroll
            for (int r = 0; r < 4; r++) acc5[r] += s1s[w][r][i2] * wv;
        }
#pragma unroll
        for (int r = 0; r < 4; r++) {
            const float h2 = silu_f(acc5[r]);
            float q0 = h2 * wq0, q1 = h2 * wq1;
            RED64(q0); RED64(q1);
            if (ln == 0) {
                const int nl = r * 2 + w;
                const int n = node0 + nl;
                const float gate = q1 + sc2b2[1];
                const float l0o  = q0 + sc2b2[0];
                l0v[n] = l0o;
                l1v[(size_t)n * 3 + 0] = gate * g0[r];
                l1v[(size_t)n * 3 + 1] = gate * g1[r];
                l1v[(size_t)n * 3 + 2] = gate * g2[r];
                gateS[nl] = gate;
                l0S[nl]   = l0o;
            }
        }
    }
    __syncthreads();

    // P-emit tail: layout [node][h<30][8] = {pv0,pv1,pv2,pr0,pr1,pr2,ps,0}
    {
        const int nl = t >> 4;          // 0..7
        const int q  = t & 15;          // 0..15
        const int n  = node0 + nl;
        const float lj0 = gateS[nl] * pwp[nl][1];
        const float lj1 = gateS[nl] * pwp[nl][3];
        const float lj2 = gateS[nl] * pwp[nl][5];
        const float l0j = l0S[nl];
        const float pj0 = pos[n * 3 + 0], pj1 = pos[n * 3 + 1], pj2 = pos[n * 3 + 2];
        float* Pj = P + (size_t)n * PSTR;
        for (int h = q; h < 30; h += 16) {
            float o[8];
#pragma unroll
            for (int a = 0; a < 3; a++) {
                o[a]     = lj0 * vvW1[(3 * a + 0) * 30 + h]
                         + lj1 * vvW1[(3 * a + 1) * 30 + h]
                         + lj2 * vvW1[(3 * a + 2) * 30 + h];
                o[3 + a] = pj0 * vrW1[(3 * a + 0) * 30 + h]
                         + pj1 * vrW1[(3 * a + 1) * 30 + h]
                         + pj2 * vrW1[(3 * a + 2) * 30 + h];
            }
            o[6] = sb1[h] + l0j * sW1[30 + h];
            o[7] = 0.0f;
            *(float4*)&Pj[h * 8 + 0] = *(float4*)&o[0];
            *(float4*)&Pj[h * 8 + 4] = *(float4*)&o[4];
        }
    }
}

// ---------- pair kernel v7 (R9, best: 82.4us): pk_fma, SGPR weight pairs ----
// Grid (A/4, B), 192 threads: g = t>=96, j = t%96; thread owns i = ni0, ni0+1.
// Packing axis = OUTPUT channels (l-pairs / h-pairs) so weight pairs are
// contiguous + wave-uniform (SGPR operand); silu/t9 operands broadcast via
// op_sel -> no splat movs. Keep unroll 2 (full unroll = I$ overflow, R10).
__global__ __launch_bounds__(192)
void pair_k(const float* __restrict__ l0v, const float* __restrict__ l1v,
            const float* __restrict__ P,
            const float* __restrict__ vvb1, const float* __restrict__ vrb1,
            const float* __restrict__ sW1,
            const float* __restrict__ vvW2, const float* __restrict__ vrW2,
            const float* __restrict__ sW2,
            const float* __restrict__ vvb2, const float* __restrict__ vrb2,
            const float* __restrict__ sb2,
            const float* __restrict__ hW1,  const float* __restrict__ hb1,
            const float* __restrict__ hW2,  const float* __restrict__ hb2,
            float* __restrict__ out) {
    const int t = threadIdx.x;
    const int b = blockIdx.y;
    const int g = (t >= 96) ? 1 : 0;
    const int j = t - g * 96;
    const int i0 = blockIdx.x * 4 + g * 2;
    const int ni0 = b * A_ATOMS + i0;       // thread: i = ni0, ni0+1
    const int nj  = b * A_ATOMS + j;
    const float* Pj = P + (size_t)nj * PSTR;

    const float li0x = l1v[ni0 * 3 + 0], li0y = l1v[ni0 * 3 + 1], li0z = l1v[ni0 * 3 + 2];
    const float li1x = l1v[(ni0 + 1) * 3 + 0], li1y = l1v[(ni0 + 1) * 3 + 1],
                li1z = l1v[(ni0 + 1) * 3 + 2];
    const float s00 = l0v[ni0], s01 = l0v[ni0 + 1];

    // t9 accumulators packed along l: tA?[lp] = (t9[2lp], t9[2lp+1]); t8 = t9[8]
    v2f tA0[4], tA1[4];
    float t80, t81;
#pragma unroll
    for (int lp = 0; lp < 4; lp++) {
        v2f tb = { vvb2[2 * lp] + vrb2[2 * lp] + sb2[2 * lp],
                   vvb2[2 * lp + 1] + vrb2[2 * lp + 1] + sb2[2 * lp + 1] };
        tA0[lp] = tb; tA1[lp] = tb;
    }
    t80 = t81 = vvb2[8] + vrb2[8] + sb2[8];

#pragma unroll 2
    for (int h = 0; h < 30; h++) {
        const float4 w0 = *(const float4*)&Pj[h * 8 + 0];
        const float4 w1 = *(const float4*)&Pj[h * 8 + 4];
        const float bv = vvb1[h], br = vrb1[h], sw = sW1[h];
        const u64 wv0 = ldw2(vvW2 + h * 9 + 0), wv1 = ldw2(vvW2 + h * 9 + 2);
        const u64 wv2 = ldw2(vvW2 + h * 9 + 4), wv3 = ldw2(vvW2 + h * 9 + 6);
        const u64 wr0 = ldw2(vrW2 + h * 9 + 0), wr1 = ldw2(vrW2 + h * 9 + 2);
        const u64 wr2 = ldw2(vrW2 + h * 9 + 4), wr3 = ldw2(vrW2 + h * 9 + 6);
        const u64 ws0 = ldw2(sW2 + h * 9 + 0),  ws1 = ldw2(sW2 + h * 9 + 2);
        const u64 ws2 = ldw2(sW2 + h * 9 + 4),  ws3 = ldw2(sW2 + h * 9 + 6);
        const float wv8 = vvW2[h * 9 + 8], wr8 = vrW2[h * 9 + 8], ws8 = sW2[h * 9 + 8];

        const float av0 = silu_f(w0.x * li0x + w0.y * li0y + w0.z * li0z + bv);
        const float ar0 = silu_f(w0.w * li0x + w1.x * li0y + w1.y * li0z + br);
        const float as0 = silu_f(w1.z + s00 * sw);
        const float av1 = silu_f(w0.x * li1x + w0.y * li1y + w0.z * li1z + bv);
        const float ar1 = silu_f(w0.w * li1x + w1.x * li1y + w1.y * li1z + br);
        const float as1 = silu_f(w1.z + s01 * sw);
        const v2f avp = { av0, av1 }, arp = { ar0, ar1 }, asp = { as0, as1 };

        pkfma_lo(tA0[0], avp, wv0); pkfma_lo(tA0[0], arp, wr0); pkfma_lo(tA0[0], asp, ws0);
        pkfma_lo(tA0[1], avp, wv1); pkfma_lo(tA0[1], arp, wr1); pkfma_lo(tA0[1], asp, ws1);
        pkfma_lo(tA0[2], avp, wv2); pkfma_lo(tA0[2], arp, wr2); pkfma_lo(tA0[2], asp, ws2);
        pkfma_lo(tA0[3], avp, wv3); pkfma_lo(tA0[3], arp, wr3); pkfma_lo(tA0[3], asp, ws3);
        pkfma_hi(tA1[0], avp, wv0); pkfma_hi(tA1[0], arp, wr0); pkfma_hi(tA1[0], asp, ws0);
        pkfma_hi(tA1[1], avp, wv1); pkfma_hi(tA1[1], arp, wr1); pkfma_hi(tA1[1], asp, ws1);
        pkfma_hi(tA1[2], avp, wv2); pkfma_hi(tA1[2], arp, wr2); pkfma_hi(tA1[2], asp, ws2);
        pkfma_hi(tA1[3], avp, wv3); pkfma_hi(tA1[3], arp, wr3); pkfma_hi(tA1[3], asp, ws3);
        t80 += av0 * wv8 + ar0 * wr8 + as0 * ws8;
        t81 += av1 * wv8 + ar1 * wr8 + as1 * ws8;
    }

    // ---- h-MLP 9->30->9, h processed in pairs; o packed along l -------------
    v2f oA0[4], oA1[4];
    float o80, o81;
#pragma unroll
    for (int lp = 0; lp < 4; lp++) {
        v2f ob = { hb2[2 * lp], hb2[2 * lp + 1] };
        oA0[lp] = ob; oA1[lp] = ob;
    }
    o80 = o81 = hb2[8];

    const v2f t8p0 = { t80, t80 }, t8p1 = { t81, t81 };

#pragma unroll 3
    for (int hp = 0; hp < 15; hp++) {
        const int h0 = 2 * hp, h1 = 2 * hp + 1;
        v2f a0 = { hb1[h0], hb1[h1] };
        v2f a1 = a0;
#pragma unroll
        for (int lp = 0; lp < 4; lp++) {
            const u64 wm0 = ldw2(hW1 + (2 * lp) * 30 + h0);
            const u64 wm1 = ldw2(hW1 + (2 * lp + 1) * 30 + h0);
            pkfma_lo(a0, tA0[lp], wm0); pkfma_hi(a0, tA0[lp], wm1);
            pkfma_lo(a1, tA1[lp], wm0); pkfma_hi(a1, tA1[lp], wm1);
        }
        const u64 w8 = ldw2(hW1 + 8 * 30 + h0);
        pkfma(a0, t8p0, w8);
        pkfma(a1, t8p1, w8);

        const float sx0 = silu_f(a0.x), sy0 = silu_f(a0.y);
        const float sx1 = silu_f(a1.x), sy1 = silu_f(a1.y);
        const v2f sp0 = { sx0, sy0 }, sp1 = { sx1, sy1 };

#pragma unroll
        for (int lp = 0; lp < 4; lp++) {
            const u64 u0 = ldw2(hW2 + h0 * 9 + 2 * lp);
            const u64 u1 = ldw2(hW2 + h1 * 9 + 2 * lp);
            pkfma_lo(oA0[lp], sp0, u0); pkfma_hi(oA0[lp], sp0, u1);
            pkfma_lo(oA1[lp], sp1, u0); pkfma_hi(oA1[lp], sp1, u1);
        }
        const float z0 = hW2[h0 * 9 + 8], z1 = hW2[h1 * 9 + 8];
        o80 += sx0 * z0 + sy0 * z1;
        o81 += sx1 * z0 + sy1 * z1;
    }

    // out[((b*A+i)*3+k)*288 + j*3 + l]
    float q0[9] = { oA0[0].x, oA0[0].y, oA0[1].x, oA0[1].y,
                    oA0[2].x, oA0[2].y, oA0[3].x, oA0[3].y, o80 };
    float q1[9] = { oA1[0].x, oA1[0].y, oA1[1].x, oA1[1].y,
                    oA1[2].x, oA1[2].y, oA1[3].x, oA1[3].y, o81 };
#pragma unroll
    for (int k = 0; k < 3; k++) {
        const size_t base0 = ((size_t)ni0 * 3 + k) * 288 + (size_t)j * 3;
        out[base0 + 0] = q0[3 * k + 0];
        out[base0 + 1] = q0[3 * k + 1];
        out[base0 + 2] = q0[3 * k + 2];
        const size_t base1 = base0 + 3 * 288;
        out[base1 + 0] = q1[3 * k + 0];
        out[base1 + 1] = q1[3 * k + 1];
        out[base1 + 2] = q1[3 * k + 2];
    }
}

extern "C" void kernel_launch(void* const* d_in, const int* in_sizes, int n_in,
                              void* d_out, int out_size, void* d_ws, size_t ws_size,
                              hipStream_t stream) {
    const float* pos   = (const float*)d_in[0];
    const float* srep  = (const float*)d_in[1];
    const float* vrep  = (const float*)d_in[2];
    const float* mixW1 = (const float*)d_in[3];
    const float* sc1W1 = (const float*)d_in[4];
    const float* sc1b1 = (const float*)d_in[5];
    const float* sc1W2 = (const float*)d_in[6];
    const float* sc1b2 = (const float*)d_in[7];
    const float* mixW2 = (const float*)d_in[8];
    const float* sc2W1 = (const float*)d_in[9];
    const float* sc2b1 = (const float*)d_in[10];
    const float* sc2W2 = (const float*)d_in[11];
    const float* sc2b2 = (const float*)d_in[12];
    const float* vvW1  = (const float*)d_in[13];
    const float* vvb1  = (const float*)d_in[14];
    const float* vvW2  = (const float*)d_in[15];
    const float* vvb2  = (const float*)d_in[16];
    const float* vrW1  = (const float*)d_in[17];
    const float* vrb1  = (const float*)d_in[18];
    const float* vrW2  = (const float*)d_in[19];
    const float* vrb2  = (const float*)d_in[20];
    const float* sW1   = (const float*)d_in[21];
    const float* sb1   = (const float*)d_in[22];
    const float* sW2   = (const float*)d_in[23];
    const float* sb2   = (const float*)d_in[24];
    const float* hW1   = (const float*)d_in[25];
    const float* hb1   = (const float*)d_in[26];
    const float* hW2   = (const float*)d_in[27];
    const float* hb2   = (const float*)d_in[28];

    float* ws  = (float*)d_ws;
    float* P   = ws;                               // PSTR*NNODES floats
    float* l0v = P + (size_t)PSTR * NNODES;        // 12,288
    float* l1v = l0v + NNODES;                     // 36,864
    float* outf = (float*)d_out;

    // 1. fused node stage -> l0, l1, P
    node_k<<<NNODES / NB, 128, 0, stream>>>(
        vrep, mixW1, srep,
        sc1W1, sc1b1, sc1W2, sc1b2,
        mixW2, sc2W1, sc2b1, sc2W2, sc2b2,
        pos, vvW1, vrW1, sW1, sb1,
        l0v, l1v, P);

    // 2. pair stage (2 i per thread, packed v_pk_fma_f32)
    pair_k<<<dim3(A_ATOMS / 4, BATCH), 192, 0, stream>>>(
        l0v, l1v, P,
        vvb1, vrb1, sW1,
        vvW2, vrW2, sW2,
        vvb2, vrb2, sb2,
        hW1, hb1, hW2, hb2,
        outf);
}